// Round 4
// baseline (596.967 us; speedup 1.0000x reference)
//
#include <hip/hip_runtime.h>
#include <hip/hip_bf16.h>
#include <stdint.h>

// Problem: B=4,H=16,L=2048,D=128, fp32 in/out, softmax(Q@K^T * 1.0) @ V
// Strategy: flash attention, bf16 MFMA with hi/lo split emulation of fp32
// (3 of 4 cross products => ~1e-4 output error), swapped QK^T so softmax is
// in-register, V^T staged hi|lo-packed + XOR-swizzled for conflict-free b128.
#define LL    2048
#define DD    128
#define KVB   32
#define NT    (LL / KVB)      // 64 KV tiles
#define WAVES 8
#define QW    32              // q rows per wave
#define QB    (QW * WAVES)    // 256 q rows per block

// ---- LDS layout (per buffer) ----
#define KROW     136                  // bf16 elems per K row (128 + 8 pad) -> 272B stride, 16B aligned
#define KPLANE_B (32 * KROW * 2)      // 8704 B per K plane (hi or lo)
#define VROW     36                   // u32 per V^T row (32 + 4 pad; pad is load-bearing for the swizzle)
#define VT_B     (DD * VROW * 4)      // 18432 B
#define KHI_OFF  0
#define KLO_OFF  KPLANE_B
#define VT_OFF   (2 * KPLANE_B)       // 17408
#define BUF_B    (VT_OFF + VT_B)      // 35840
#define SMEM_B   (2 * BUF_B)          // 71680 (dynamic LDS, double buffered; >64KB ok via
                                      // hipFuncSetAttribute — cf. 128KB m201 template)

typedef __attribute__((ext_vector_type(4))) float          f32x4;
typedef __attribute__((ext_vector_type(8))) __bf16         bf16x8;
typedef __attribute__((ext_vector_type(8))) unsigned short u16x8;
typedef __attribute__((ext_vector_type(4))) unsigned int   u32x4;

// float -> bf16 (round-to-nearest-even), manual: bit-exact with _rn for finite x
static __device__ __forceinline__ unsigned bf16_rne(float x) {
  unsigned u = __builtin_bit_cast(unsigned, x);
  u += 0x7fffu + ((u >> 16) & 1u);
  return u >> 16;
}
// pack two floats -> two bf16 in one u32 (x0 in low half)
static __device__ __forceinline__ unsigned pk_bf2(float x0, float x1) {
  return bf16_rne(x0) | (bf16_rne(x1) << 16);
}
// fp32 -> bf16 hi + bf16 lo (residual), pairwise packed
static __device__ __forceinline__ void split_pk(float x0, float x1, unsigned& hi, unsigned& lo) {
  hi = pk_bf2(x0, x1);
  const float h0 = __builtin_bit_cast(float, hi << 16);
  const float h1 = __builtin_bit_cast(float, hi & 0xffff0000u);
  lo = pk_bf2(x0 - h0, x1 - h1);
}
static __device__ __forceinline__ f32x4 mfma16(u16x8 a, u16x8 b, f32x4 c) {
  return __builtin_amdgcn_mfma_f32_16x16x32_bf16(
      __builtin_bit_cast(bf16x8, a), __builtin_bit_cast(bf16x8, b), c, 0, 0, 0);
}

__global__ __launch_bounds__(512, 2) void fattn_kernel(
    const float* __restrict__ Qg, const float* __restrict__ Kg,
    const float* __restrict__ Vg, float* __restrict__ Og)
{
  extern __shared__ char smem[];

  const int bid  = (int)blockIdx.x;
  // bid%8 == XCD (round-robin dispatch): give each XCD 8 whole heads so a
  // head's 8 q-blocks share K/V streams in one XCD's L2.
  const int head = ((bid & 7) << 3) | (bid >> 6);
  const int qblk = (bid >> 3) & 7;
  const size_t hb = (size_t)head * (size_t)(LL * DD);
  const float* __restrict__ Qh = Qg + hb;
  const float* __restrict__ Kh = Kg + hb;
  const float* __restrict__ Vh = Vg + hb;
  float* __restrict__       Oh = Og + hb;

  const int tid  = (int)threadIdx.x;
  const int lane = tid & 63;
  const int wid  = tid >> 6;
  const int l15  = lane & 15;
  const int g    = lane >> 4;       // 16-lane group (MFMA k-group)
  const int q0   = qblk * QB + wid * QW;

  // ---------- Q fragments, resident in registers (bf16 hi/lo) ----------
  // B-operand of S^T mfma: slot j of lane = Q[q0+qt*16+l15][dc*32 + g*8 + j]
  // (same contiguous slot->k map as the K A-frag: correctness needs only
  //  sigma_A == sigma_B and bijectivity, not the true HW k-order)
  u16x8 qhi[2][4], qlo[2][4];
#pragma unroll
  for (int qt = 0; qt < 2; ++qt) {
#pragma unroll
    for (int dc = 0; dc < 4; ++dc) {
      const float* p = Qh + (size_t)(q0 + qt * 16 + l15) * DD + dc * 32 + g * 8;
      const f32x4 a = *(const f32x4*)(p);
      const f32x4 b = *(const f32x4*)(p + 4);
      union { u16x8 v; unsigned u[4]; } H, L;
      split_pk(a[0], a[1], H.u[0], L.u[0]);
      split_pk(a[2], a[3], H.u[1], L.u[1]);
      split_pk(b[0], b[1], H.u[2], L.u[2]);
      split_pk(b[2], b[3], H.u[3], L.u[3]);
      qhi[qt][dc] = H.v; qlo[qt][dc] = L.v;
    }
  }

  // ---------- staging indices ----------
  const int kvr  = tid >> 4;          // 0..31: kv row within tile
  const int d0   = (tid & 15) * 8;    // 0..120: d base (8 elements per thread)
  const int vswz = ((d0 >> 3) & 7) << 2;

  f32x4 kA, kB, vA, vB;   // prefetch registers (issue-early / write-late)

  // global loads for tile 0
  {
    const float* kp = Kh + (size_t)kvr * DD + d0;
    const float* vp = Vh + (size_t)kvr * DD + d0;
    kA = *(const f32x4*)kp; kB = *(const f32x4*)(kp + 4);
    vA = *(const f32x4*)vp; vB = *(const f32x4*)(vp + 4);
  }

  auto stage = [&](int b) {
    unsigned short* kh = (unsigned short*)(smem + b * BUF_B + KHI_OFF);
    unsigned short* kl = (unsigned short*)(smem + b * BUF_B + KLO_OFF);
    unsigned*       vt = (unsigned*)(smem + b * BUF_B + VT_OFF);
    // K row-major bf16 hi/lo planes
    union { u16x8 v; unsigned u[4]; } H, L;
    split_pk(kA[0], kA[1], H.u[0], L.u[0]);
    split_pk(kA[2], kA[3], H.u[1], L.u[1]);
    split_pk(kB[0], kB[1], H.u[2], L.u[2]);
    split_pk(kB[2], kB[3], H.u[3], L.u[3]);
    *(u16x8*)(kh + kvr * KROW + d0) = H.v;
    *(u16x8*)(kl + kvr * KROW + d0) = L.v;
    // V transposed: vt[d][kv ^ swz(d)] = hi | lo<<16 (one u32 per (d,kv))
    const float vv[8] = {vA[0], vA[1], vA[2], vA[3], vB[0], vB[1], vB[2], vB[3]};
#pragma unroll
    for (int i = 0; i < 4; ++i) {
      unsigned h, l;
      split_pk(vv[2 * i], vv[2 * i + 1], h, l);
      const unsigned w0 = (h & 0xffffu) | (l << 16);
      const unsigned w1 = (h >> 16) | (l & 0xffff0000u);
      const int d = d0 + 2 * i;
      vt[(size_t)d * VROW + (kvr ^ vswz)]       = w0;
      vt[(size_t)(d + 1) * VROW + (kvr ^ vswz)] = w1;
    }
  };

  stage(0);
  __syncthreads();

  f32x4 oacc[8][2];
#pragma unroll
  for (int dt = 0; dt < 8; ++dt) {
    oacc[dt][0] = f32x4{0.f, 0.f, 0.f, 0.f};
    oacc[dt][1] = f32x4{0.f, 0.f, 0.f, 0.f};
  }
  float mrun[2] = {-INFINITY, -INFINITY};
  float lrun[2] = {0.f, 0.f};

  for (int t = 0; t < NT; ++t) {
    const int cb = t & 1;
    if (t + 1 < NT) {   // issue next tile's global loads early (latency hides under MFMA)
      const float* kp = Kh + (size_t)((t + 1) * KVB + kvr) * DD + d0;
      const float* vp = Vh + (size_t)((t + 1) * KVB + kvr) * DD + d0;
      kA = *(const f32x4*)kp; kB = *(const f32x4*)(kp + 4);
      vA = *(const f32x4*)vp; vB = *(const f32x4*)(vp + 4);
    }

    // ---- S^T = K · Q^T (32kv × 32q), fp32 precision via hi/lo (3 of 4 products) ----
    const unsigned short* kh = (const unsigned short*)(smem + cb * BUF_B + KHI_OFF);
    const unsigned short* kl = (const unsigned short*)(smem + cb * BUF_B + KLO_OFF);
    f32x4 sacc[2][2];
    sacc[0][0] = f32x4{0.f,0.f,0.f,0.f}; sacc[0][1] = f32x4{0.f,0.f,0.f,0.f};
    sacc[1][0] = f32x4{0.f,0.f,0.f,0.f}; sacc[1][1] = f32x4{0.f,0.f,0.f,0.f};
#pragma unroll
    for (int dc = 0; dc < 4; ++dc) {
      u16x8 ah[2], al[2];
#pragma unroll
      for (int kvt = 0; kvt < 2; ++kvt) {
        const int off = (kvt * 16 + l15) * KROW + dc * 32 + g * 8;
        ah[kvt] = *(const u16x8*)(kh + off);
        al[kvt] = *(const u16x8*)(kl + off);
      }
#pragma unroll
      for (int kvt = 0; kvt < 2; ++kvt) {
#pragma unroll
        for (int qt = 0; qt < 2; ++qt) {
          sacc[kvt][qt] = mfma16(ah[kvt], qhi[qt][dc], sacc[kvt][qt]);
          sacc[kvt][qt] = mfma16(ah[kvt], qlo[qt][dc], sacc[kvt][qt]);
          sacc[kvt][qt] = mfma16(al[kvt], qhi[qt][dc], sacc[kvt][qt]);
        }
      }
    }

    // ---- online softmax: lane holds 8 kv-values for q = qt*16+l15 ----
    // sacc[kvt][qt] reg r = S^T[kv = kvt*16 + g*4 + r][q]; over g,r,kvt that
    // covers kv 0..31, so reduce = 7 in-lane fmax + shfl_xor(16,32).
    u16x8 phi[2], plo[2];
#pragma unroll
    for (int qt = 0; qt < 2; ++qt) {
      float mx = sacc[0][qt][0];
      mx = fmaxf(mx, sacc[0][qt][1]); mx = fmaxf(mx, sacc[0][qt][2]); mx = fmaxf(mx, sacc[0][qt][3]);
      mx = fmaxf(mx, sacc[1][qt][0]); mx = fmaxf(mx, sacc[1][qt][1]);
      mx = fmaxf(mx, sacc[1][qt][2]); mx = fmaxf(mx, sacc[1][qt][3]);
      mx = fmaxf(mx, __shfl_xor(mx, 16));
      mx = fmaxf(mx, __shfl_xor(mx, 32));
      const float mnew  = fmaxf(mrun[qt], mx);
      const float alpha = __expf(mrun[qt] - mnew);
      mrun[qt] = mnew;
      float p[8];
      float rs = 0.f;
#pragma unroll
      for (int j = 0; j < 8; ++j) {
        const float e = __expf(sacc[j >> 2][qt][j & 3] - mnew);
        p[j] = e; rs += e;
      }
      rs += __shfl_xor(rs, 16);
      rs += __shfl_xor(rs, 32);
      lrun[qt] = lrun[qt] * alpha + rs;
#pragma unroll
      for (int dt = 0; dt < 8; ++dt) oacc[dt][qt] *= alpha;
      // P^T B-frag: slot j = P[kv = g*4 + (j&3) + 16*(j>>2)][q]  (matches V^T A-frag map)
      union { u16x8 v; unsigned u[4]; } PH, PL;
#pragma unroll
      for (int i = 0; i < 4; ++i) split_pk(p[2 * i], p[2 * i + 1], PH.u[i], PL.u[i]);
      phi[qt] = PH.v; plo[qt] = PL.v;
    }

    // ---- O^T += V^T · P^T : A-frag slot j = V[g*4+(j&3)+16*(j>>2)][d = dt*16+l15] ----
    const unsigned* vt = (const unsigned*)(smem + cb * BUF_B + VT_OFF);
#pragma unroll
    for (int dt = 0; dt < 8; ++dt) {
      const int d  = dt * 16 + l15;
      const int sz = ((d >> 3) & 7) << 2;
      const unsigned* row = vt + (size_t)d * VROW;
      const u32x4 r0 = *(const u32x4*)(row + ((g * 4) ^ sz));
      const u32x4 r1 = *(const u32x4*)(row + ((16 + g * 4) ^ sz));
      union { u16x8 v; unsigned u[4]; } VH, VL;
      VH.u[0] = __builtin_amdgcn_perm(r0[1], r0[0], 0x05040100u);
      VH.u[1] = __builtin_amdgcn_perm(r0[3], r0[2], 0x05040100u);
      VH.u[2] = __builtin_amdgcn_perm(r1[1], r1[0], 0x05040100u);
      VH.u[3] = __builtin_amdgcn_perm(r1[3], r1[2], 0x05040100u);
      VL.u[0] = __builtin_amdgcn_perm(r0[1], r0[0], 0x07060302u);
      VL.u[1] = __builtin_amdgcn_perm(r0[3], r0[2], 0x07060302u);
      VL.u[2] = __builtin_amdgcn_perm(r1[1], r1[0], 0x07060302u);
      VL.u[3] = __builtin_amdgcn_perm(r1[3], r1[2], 0x07060302u);
#pragma unroll
      for (int qt = 0; qt < 2; ++qt) {
        oacc[dt][qt] = mfma16(VH.v, phi[qt], oacc[dt][qt]);
        oacc[dt][qt] = mfma16(VH.v, plo[qt], oacc[dt][qt]);
        oacc[dt][qt] = mfma16(VL.v, phi[qt], oacc[dt][qt]);
      }
    }

    if (t + 1 < NT) stage(cb ^ 1);   // write-late into the other buffer
    __syncthreads();                  // single barrier per iteration
  }

  // ---- epilogue: O[q][d] = oacc^T / l ; C layout: col=l15=q, row=g*4+r=d within dt ----
#pragma unroll
  for (int qt = 0; qt < 2; ++qt) {
    const float inv = 1.0f / lrun[qt];
    float* orow = Oh + (size_t)(q0 + qt * 16 + l15) * DD + g * 4;
#pragma unroll
    for (int dt = 0; dt < 8; ++dt) {
      f32x4 o = oacc[dt][qt];
      o *= inv;
      *(f32x4*)(orow + dt * 16) = o;   // 16B store, 64B-line coalesced across g
    }
  }
}

extern "C" void kernel_launch(void* const* d_in, const int* in_sizes, int n_in,
                              void* d_out, int out_size, void* d_ws, size_t ws_size,
                              hipStream_t stream)
{
  (void)in_sizes; (void)n_in; (void)out_size; (void)d_ws; (void)ws_size;
  const float* Q = (const float*)d_in[0];
  const float* K = (const float*)d_in[1];
  const float* V = (const float*)d_in[2];
  float* O = (float*)d_out;

  // allow >64KB dynamic LDS (host-side, capture-safe, idempotent)
  (void)hipFuncSetAttribute((const void*)fattn_kernel,
                            hipFuncAttributeMaxDynamicSharedMemorySize, SMEM_B);

  dim3 grid(64 * (LL / QB));   // 64 heads x 8 q-blocks = 512
  dim3 block(WAVES * 64);      // 512 threads
  fattn_kernel<<<grid, block, SMEM_B, stream>>>(Q, K, V, O);
}

// Round 6
// 541.807 us; speedup vs baseline: 1.1018x; 1.1018x over previous
//
#include <hip/hip_runtime.h>
#include <hip/hip_bf16.h>
#include <stdint.h>

// Problem: B=4,H=16,L=2048,D=128, fp32 in/out, softmax(Q@K^T * 1.0) @ V
// Flash attention, bf16 MFMA hi/lo split emulation of fp32 (3 of 4 products).
// R4: cast-based bf16 packing (cvt_pk), exp2-domain softmax (Q pre-scaled by
// log2e), defer-max rescale skip (THR=8 log2), setprio around MFMA clusters.
#define LL    2048
#define DD    128
#define KVB   32
#define NT    (LL / KVB)      // 64 KV tiles
#define WAVES 8
#define QW    32              // q rows per wave
#define QB    (QW * WAVES)    // 256 q rows per block

// ---- LDS layout (per buffer) ----
#define KROW     136                  // bf16 elems per K row (128 + 8 pad) -> 272B stride
#define KPLANE_B (32 * KROW * 2)      // 8704 B per K plane (hi or lo)
#define VROW     36                   // u32 per V^T row (32 + 4 pad; load-bearing for swizzle)
#define VT_B     (DD * VROW * 4)      // 18432 B
#define KHI_OFF  0
#define KLO_OFF  KPLANE_B
#define VT_OFF   (2 * KPLANE_B)       // 17408
#define BUF_B    (VT_OFF + VT_B)      // 35840
#define SMEM_B   (2 * BUF_B)          // 71680 dynamic LDS, double buffered

#define LOG2E 1.44269504088896340736f
#define DEFER_THR 8.0f                // log2-domain defer-max threshold (p <= 2^8)

typedef __attribute__((ext_vector_type(4))) float          f32x4;
typedef __attribute__((ext_vector_type(8))) __bf16         bf16x8;
typedef __attribute__((ext_vector_type(8))) unsigned short u16x8;
typedef __attribute__((ext_vector_type(4))) unsigned int   u32x4;

// f32 -> bf16 bits via compiler cast (RNE; compiler emits v_cvt_pk_bf16_f32 pairs)
static __device__ __forceinline__ unsigned short bf16b(float x) {
  return __builtin_bit_cast(unsigned short, (__bf16)x);
}
// pack two floats -> two bf16 in one u32 (x0 in low half)
static __device__ __forceinline__ unsigned pk_bf2(float x0, float x1) {
  return (unsigned)bf16b(x0) | ((unsigned)bf16b(x1) << 16);
}
// fp32 -> bf16 hi + bf16 lo (residual), pairwise packed
static __device__ __forceinline__ void split_pk(float x0, float x1, unsigned& hi, unsigned& lo) {
  hi = pk_bf2(x0, x1);
  lo = pk_bf2(x0 - __builtin_bit_cast(float, hi << 16),
              x1 - __builtin_bit_cast(float, hi & 0xffff0000u));
}
static __device__ __forceinline__ f32x4 mfma16(u16x8 a, u16x8 b, f32x4 c) {
  return __builtin_amdgcn_mfma_f32_16x16x32_bf16(
      __builtin_bit_cast(bf16x8, a), __builtin_bit_cast(bf16x8, b), c, 0, 0, 0);
}

__global__ __launch_bounds__(512, 2) void fattn_kernel(
    const float* __restrict__ Qg, const float* __restrict__ Kg,
    const float* __restrict__ Vg, float* __restrict__ Og)
{
  extern __shared__ char smem[];

  const int bid  = (int)blockIdx.x;
  // bid%8 == XCD (round-robin dispatch): 8 whole heads per XCD for K/V L2 locality
  const int head = ((bid & 7) << 3) | (bid >> 6);
  const int qblk = (bid >> 3) & 7;
  const size_t hb = (size_t)head * (size_t)(LL * DD);
  const float* __restrict__ Qh = Qg + hb;
  const float* __restrict__ Kh = Kg + hb;
  const float* __restrict__ Vh = Vg + hb;
  float* __restrict__       Oh = Og + hb;

  const int tid  = (int)threadIdx.x;
  const int lane = tid & 63;
  const int wid  = tid >> 6;
  const int l15  = lane & 15;
  const int g    = lane >> 4;       // 16-lane group (MFMA k-group)
  const int q0   = qblk * QB + wid * QW;

  // ---------- Q fragments in registers, PRE-SCALED by log2e (exp2-domain softmax) ----------
  // B-operand of S^T mfma: slot j of lane = Q[q0+qt*16+l15][dc*32 + g*8 + j]
  u16x8 qhi[2][4], qlo[2][4];
#pragma unroll
  for (int qt = 0; qt < 2; ++qt) {
#pragma unroll
    for (int dc = 0; dc < 4; ++dc) {
      const float* p = Qh + (size_t)(q0 + qt * 16 + l15) * DD + dc * 32 + g * 8;
      f32x4 a = *(const f32x4*)(p);
      f32x4 b = *(const f32x4*)(p + 4);
      a *= LOG2E; b *= LOG2E;
      union { u16x8 v; unsigned u[4]; } H, L;
      split_pk(a[0], a[1], H.u[0], L.u[0]);
      split_pk(a[2], a[3], H.u[1], L.u[1]);
      split_pk(b[0], b[1], H.u[2], L.u[2]);
      split_pk(b[2], b[3], H.u[3], L.u[3]);
      qhi[qt][dc] = H.v; qlo[qt][dc] = L.v;
    }
  }

  // ---------- staging indices ----------
  const int kvr  = tid >> 4;          // 0..31: kv row within tile
  const int d0   = (tid & 15) * 8;    // 0..120: d base (8 elements per thread)
  const int vswz = ((d0 >> 3) & 7) << 2;

  f32x4 kA, kB, vA, vB;   // prefetch registers (issue-early / write-late)

  {
    const float* kp = Kh + (size_t)kvr * DD + d0;
    const float* vp = Vh + (size_t)kvr * DD + d0;
    kA = *(const f32x4*)kp; kB = *(const f32x4*)(kp + 4);
    vA = *(const f32x4*)vp; vB = *(const f32x4*)(vp + 4);
  }

  auto stage = [&](int b) {
    unsigned short* kh = (unsigned short*)(smem + b * BUF_B + KHI_OFF);
    unsigned short* kl = (unsigned short*)(smem + b * BUF_B + KLO_OFF);
    unsigned*       vt = (unsigned*)(smem + b * BUF_B + VT_OFF);
    union { u16x8 v; unsigned u[4]; } H, L;
    split_pk(kA[0], kA[1], H.u[0], L.u[0]);
    split_pk(kA[2], kA[3], H.u[1], L.u[1]);
    split_pk(kB[0], kB[1], H.u[2], L.u[2]);
    split_pk(kB[2], kB[3], H.u[3], L.u[3]);
    *(u16x8*)(kh + kvr * KROW + d0) = H.v;
    *(u16x8*)(kl + kvr * KROW + d0) = L.v;
    // V transposed: vt[d][kv ^ swz(d)] = hi | lo<<16 (one u32 per (d,kv))
    const float vv[8] = {vA[0], vA[1], vA[2], vA[3], vB[0], vB[1], vB[2], vB[3]};
#pragma unroll
    for (int i = 0; i < 4; ++i) {
      unsigned h, l;
      split_pk(vv[2 * i], vv[2 * i + 1], h, l);
      const unsigned w0 = (h & 0xffffu) | (l << 16);
      const unsigned w1 = (h >> 16) | (l & 0xffff0000u);
      const int d = d0 + 2 * i;
      vt[(size_t)d * VROW + (kvr ^ vswz)]       = w0;
      vt[(size_t)(d + 1) * VROW + (kvr ^ vswz)] = w1;
    }
  };

  stage(0);
  __syncthreads();

  f32x4 oacc[8][2];
#pragma unroll
  for (int dt = 0; dt < 8; ++dt) {
    oacc[dt][0] = f32x4{0.f, 0.f, 0.f, 0.f};
    oacc[dt][1] = f32x4{0.f, 0.f, 0.f, 0.f};
  }
  float mrun[2] = {-INFINITY, -INFINITY};   // in log2 domain
  float lrun[2] = {0.f, 0.f};

  for (int t = 0; t < NT; ++t) {
    const int cb = t & 1;
    if (t + 1 < NT) {   // issue next tile's global loads early
      const float* kp = Kh + (size_t)((t + 1) * KVB + kvr) * DD + d0;
      const float* vp = Vh + (size_t)((t + 1) * KVB + kvr) * DD + d0;
      kA = *(const f32x4*)kp; kB = *(const f32x4*)(kp + 4);
      vA = *(const f32x4*)vp; vB = *(const f32x4*)(vp + 4);
    }

    // ---- S^T = K · Q^T (32kv × 32q), scores in log2 domain ----
    const unsigned short* kh = (const unsigned short*)(smem + cb * BUF_B + KHI_OFF);
    const unsigned short* kl = (const unsigned short*)(smem + cb * BUF_B + KLO_OFF);
    f32x4 sacc[2][2];
    sacc[0][0] = f32x4{0.f,0.f,0.f,0.f}; sacc[0][1] = f32x4{0.f,0.f,0.f,0.f};
    sacc[1][0] = f32x4{0.f,0.f,0.f,0.f}; sacc[1][1] = f32x4{0.f,0.f,0.f,0.f};
    __builtin_amdgcn_s_setprio(1);
#pragma unroll
    for (int dc = 0; dc < 4; ++dc) {
      u16x8 ah[2], al[2];
#pragma unroll
      for (int kvt = 0; kvt < 2; ++kvt) {
        const int off = (kvt * 16 + l15) * KROW + dc * 32 + g * 8;
        ah[kvt] = *(const u16x8*)(kh + off);
        al[kvt] = *(const u16x8*)(kl + off);
      }
#pragma unroll
      for (int kvt = 0; kvt < 2; ++kvt) {
#pragma unroll
        for (int qt = 0; qt < 2; ++qt) {
          sacc[kvt][qt] = mfma16(ah[kvt], qhi[qt][dc], sacc[kvt][qt]);
          sacc[kvt][qt] = mfma16(ah[kvt], qlo[qt][dc], sacc[kvt][qt]);
          sacc[kvt][qt] = mfma16(al[kvt], qhi[qt][dc], sacc[kvt][qt]);
        }
      }
    }
    __builtin_amdgcn_s_setprio(0);

    // ---- online softmax (exp2 domain, defer-max) ----
    u16x8 phi[2], plo[2];
#pragma unroll
    for (int qt = 0; qt < 2; ++qt) {
      float mx = sacc[0][qt][0];
      mx = fmaxf(mx, sacc[0][qt][1]); mx = fmaxf(mx, sacc[0][qt][2]); mx = fmaxf(mx, sacc[0][qt][3]);
      mx = fmaxf(mx, sacc[1][qt][0]); mx = fmaxf(mx, sacc[1][qt][1]);
      mx = fmaxf(mx, sacc[1][qt][2]); mx = fmaxf(mx, sacc[1][qt][3]);
      mx = fmaxf(mx, __shfl_xor(mx, 16));
      mx = fmaxf(mx, __shfl_xor(mx, 32));
      // defer-max: skip rescale when no row grew past m+THR (wave-uniform test)
      if (!__all(mx <= mrun[qt] + DEFER_THR)) {
        const float mnew  = fmaxf(mrun[qt], mx);
        const float alpha = __builtin_amdgcn_exp2f(mrun[qt] - mnew);
        mrun[qt] = mnew;
        lrun[qt] *= alpha;
#pragma unroll
        for (int dt = 0; dt < 8; ++dt) oacc[dt][qt] *= alpha;
      }
      const float mcur = mrun[qt];
      float p[8];
      float rs = 0.f;
#pragma unroll
      for (int j = 0; j < 8; ++j) {
        const float e = __builtin_amdgcn_exp2f(sacc[j >> 2][qt][j & 3] - mcur);
        p[j] = e; rs += e;
      }
      rs += __shfl_xor(rs, 16);
      rs += __shfl_xor(rs, 32);
      lrun[qt] += rs;
      // P^T B-frag: slot j = P[kv = g*4 + (j&3) + 16*(j>>2)][q]  (matches V^T A-frag map)
      union { u16x8 v; unsigned u[4]; } PH, PL;
#pragma unroll
      for (int i = 0; i < 4; ++i) split_pk(p[2 * i], p[2 * i + 1], PH.u[i], PL.u[i]);
      phi[qt] = PH.v; plo[qt] = PL.v;
    }

    // ---- O^T += V^T · P^T : A-frag slot j = V[g*4+(j&3)+16*(j>>2)][d = dt*16+l15] ----
    const unsigned* vt = (const unsigned*)(smem + cb * BUF_B + VT_OFF);
    __builtin_amdgcn_s_setprio(1);
#pragma unroll
    for (int dt = 0; dt < 8; ++dt) {
      const int d  = dt * 16 + l15;
      const int sz = ((d >> 3) & 7) << 2;
      const unsigned* row = vt + (size_t)d * VROW;
      const u32x4 r0 = *(const u32x4*)(row + ((g * 4) ^ sz));
      const u32x4 r1 = *(const u32x4*)(row + ((16 + g * 4) ^ sz));
      union { u16x8 v; unsigned u[4]; } VH, VL;
      VH.u[0] = __builtin_amdgcn_perm(r0[1], r0[0], 0x05040100u);
      VH.u[1] = __builtin_amdgcn_perm(r0[3], r0[2], 0x05040100u);
      VH.u[2] = __builtin_amdgcn_perm(r1[1], r1[0], 0x05040100u);
      VH.u[3] = __builtin_amdgcn_perm(r1[3], r1[2], 0x05040100u);
      VL.u[0] = __builtin_amdgcn_perm(r0[1], r0[0], 0x07060302u);
      VL.u[1] = __builtin_amdgcn_perm(r0[3], r0[2], 0x07060302u);
      VL.u[2] = __builtin_amdgcn_perm(r1[1], r1[0], 0x07060302u);
      VL.u[3] = __builtin_amdgcn_perm(r1[3], r1[2], 0x07060302u);
#pragma unroll
      for (int qt = 0; qt < 2; ++qt) {
        oacc[dt][qt] = mfma16(VH.v, phi[qt], oacc[dt][qt]);
        oacc[dt][qt] = mfma16(VH.v, plo[qt], oacc[dt][qt]);
        oacc[dt][qt] = mfma16(VL.v, phi[qt], oacc[dt][qt]);
      }
    }
    __builtin_amdgcn_s_setprio(0);

    if (t + 1 < NT) stage(cb ^ 1);   // write-late into the other buffer
    __syncthreads();                  // single barrier per iteration
  }

  // ---- epilogue: O[q][d] = oacc^T / l ----
#pragma unroll
  for (int qt = 0; qt < 2; ++qt) {
    const float inv = 1.0f / lrun[qt];
    float* orow = Oh + (size_t)(q0 + qt * 16 + l15) * DD + g * 4;
#pragma unroll
    for (int dt = 0; dt < 8; ++dt) {
      f32x4 o = oacc[dt][qt];
      o *= inv;
      *(f32x4*)(orow + dt * 16) = o;
    }
  }
}

extern "C" void kernel_launch(void* const* d_in, const int* in_sizes, int n_in,
                              void* d_out, int out_size, void* d_ws, size_t ws_size,
                              hipStream_t stream)
{
  (void)in_sizes; (void)n_in; (void)out_size; (void)d_ws; (void)ws_size;
  const float* Q = (const float*)d_in[0];
  const float* K = (const float*)d_in[1];
  const float* V = (const float*)d_in[2];
  float* O = (float*)d_out;

  (void)hipFuncSetAttribute((const void*)fattn_kernel,
                            hipFuncAttributeMaxDynamicSharedMemorySize, SMEM_B);

  dim3 grid(64 * (LL / QB));   // 64 heads x 8 q-blocks = 512
  dim3 block(WAVES * 64);      // 512 threads
  fattn_kernel<<<grid, block, SMEM_B, stream>>>(Q, K, V, O);
}